// Round 4
// baseline (71.914 us; speedup 1.0000x reference)
//
#include <hip/hip_runtime.h>
#include <hip/hip_bf16.h>
#include <cstddef>

// out[b,d,p] = sum_{t=0..62} filt[t] * act[b, (d+31-t) & 511, p]
// Banded circulant via mfma_f32_32x32x16_bf16 (6 K-blocks per 32-row d-tile).
// 2-tile-per-block software pipeline: prefetch next tile's globals to regs
// before current tile's compute; double-buffered LDS (2 x 32 KB).

#define NC    512
#define HW    3136          // 56*56
#define NT    32            // hw positions per tile
#define NTILE 98            // tiles per batch
#define NB    32
#define TPB   256
#define TPW   2             // tiles per block
#define NPAIR (NTILE / TPW) // 49

typedef __attribute__((ext_vector_type(8)))  short bf16x8;
typedef __attribute__((ext_vector_type(4)))  float f32x4;
typedef __attribute__((ext_vector_type(16))) float f32x16;

__device__ __forceinline__ short f2bf(float f) {
    union { __hip_bfloat16 h; short s; } u;
    u.h = __float2bfloat16(f);
    return u.s;
}

__device__ __forceinline__ int swzf(int hw) {
    return (((hw & 7) ^ (hw >> 3)) << 4);
}

__device__ __forceinline__ void load_tile(const float* __restrict__ gb,
                                          int wv, int g, int q, f32x4 (&r)[16]) {
    #pragma unroll
    for (int j = 0; j < 8; ++j) {
        const int r0 = wv * 128 + j * 16 + 2 * g;
        r[2 * j]     = *reinterpret_cast<const f32x4*>(gb + (size_t)r0 * HW + 4 * q);
        r[2 * j + 1] = *reinterpret_cast<const f32x4*>(gb + (size_t)(r0 + 1) * HW + 4 * q);
    }
}

__device__ __forceinline__ void store_tile(unsigned short* __restrict__ dst,
                                           int wv, int g, int q, const f32x4 (&r)[16]) {
    #pragma unroll
    for (int j = 0; j < 8; ++j) {
        const int r0 = wv * 128 + j * 16 + 2 * g;
        #pragma unroll
        for (int t4 = 0; t4 < 4; ++t4) {
            const int hw = 4 * q + t4;
            const unsigned int pk = (unsigned int)(unsigned short)f2bf(r[2 * j][t4])
                                  | ((unsigned int)(unsigned short)f2bf(r[2 * j + 1][t4]) << 16);
            const int byte = hw * (NC * 2) + ((r0 * 2) ^ swzf(hw));
            *reinterpret_cast<unsigned int*>(reinterpret_cast<char*>(dst) + byte) = pk;
        }
    }
}

__global__ __launch_bounds__(TPB, 2)
void toeplitz_pipe_kernel(const float* __restrict__ act,
                          const float* __restrict__ filt,
                          float* __restrict__ out) {
    // bf16 x-tiles [hw][c]: byte = hw*1024 + ((c*2) ^ swzf(hw)).  2 x 32 KB.
    __shared__ __align__(16) unsigned short xs[2][NT * NC];

    const int tid = threadIdx.x;
    const int wv  = tid >> 6;
    const int ln  = tid & 63;
    const int bx  = blockIdx.x;
    const int b   = bx / NPAIR;
    const int pr  = bx - b * NPAIR;
    const int t0  = pr * TPW;

    // ---- A fragments: A_delta[r,k] = filt[delta + 31 + r - k] (0 outside)
    // lane: r = ln&31, k = (ln>>5)*8 + i.  delta(m) = 32 - 16*m, m=0..5
    const int r_a = ln & 31;
    const int k0  = (ln >> 5) * 8;
    bf16x8 af[6];
    #pragma unroll
    for (int m = 0; m < 6; ++m) {
        const int delta = 32 - 16 * m;
        #pragma unroll
        for (int i = 0; i < 8; ++i) {
            const int t = delta + 31 + r_a - (k0 + i);
            af[m][i] = (t >= 0 && t < 63) ? f2bf(filt[t]) : (short)0;
        }
    }

    const int g = ln >> 3;      // 0..7 row-pair group
    const int q = ln & 7;       // hw quad
    const float* gbase = act + (size_t)b * NC * HW;

    // ---- prologue: stage tile t0 into buffer 0
    {
        f32x4 R[16];
        load_tile(gbase + (size_t)t0 * NT, wv, g, q, R);
        store_tile(xs[0], wv, g, q, R);
    }
    __syncthreads();

    const int hwl     = ln & 31;
    const int rowbyte = hwl * (NC * 2);
    const int swzv    = swzf(hwl);
    const int kbv     = (ln >> 5) * 16;
    const int rhalf   = (ln >> 5) * 4;
    const int cbase   = wv * 128 - 32;

    #pragma unroll
    for (int i = 0; i < TPW; ++i) {
        // prefetch next tile to registers (issue before compute; no wait here)
        f32x4 Rn[16];
        if (i + 1 < TPW)
            load_tile(gbase + (size_t)(t0 + i + 1) * NT, wv, g, q, Rn);

        // compute tile i from buffer i
        const char* xb = reinterpret_cast<const char*>(xs[i & 1]);
        bf16x8 w[12];
        #pragma unroll
        for (int u = 0; u < 12; ++u) {
            const int c0 = (cbase + 16 * u) & (NC - 1);
            w[u] = *reinterpret_cast<const bf16x8*>(xb + rowbyte + (((c0 * 2) + kbv) ^ swzv));
        }
        float* ob = out + (size_t)b * NC * HW + (size_t)(t0 + i) * NT + hwl;
        #pragma unroll
        for (int j = 0; j < 4; ++j) {
            const int d0 = wv * 128 + j * 32;
            f32x16 acc;
            #pragma unroll
            for (int r = 0; r < 16; ++r) acc[r] = 0.0f;
            #pragma unroll
            for (int m = 0; m < 6; ++m)     // c0 = d0-32+16m, delta = 32-16m
                acc = __builtin_amdgcn_mfma_f32_32x32x16_bf16(af[m], w[2 * j + m], acc, 0, 0, 0);
            #pragma unroll
            for (int r = 0; r < 16; ++r) {
                const int row = d0 + (r & 3) + 8 * (r >> 2) + rhalf;
                __builtin_nontemporal_store(acc[r], ob + (size_t)row * HW);
            }
        }

        // publish next tile into the other buffer
        if (i + 1 < TPW) {
            store_tile(xs[(i + 1) & 1], wv, g, q, Rn);
            __syncthreads();
        }
    }
}

extern "C" void kernel_launch(void* const* d_in, const int* in_sizes, int n_in,
                              void* d_out, int out_size, void* d_ws, size_t ws_size,
                              hipStream_t stream) {
    const float* act  = (const float*)d_in[0];   // (32, 512, 56, 56) f32
    const float* filt = (const float*)d_in[1];   // (1, 1, 63) f32
    float* out = (float*)d_out;                  // (32, 512, 56, 56) f32
    dim3 grid(NB * NPAIR);    // 1568
    dim3 block(TPB);
    hipLaunchKernelGGL(toeplitz_pipe_kernel, grid, block, 0, stream,
                       act, filt, out);
}